// Round 1
// baseline (945.437 us; speedup 1.0000x reference)
//
#include <hip/hip_runtime.h>

#define NN 100000
#define NE 1600000
#define NG 512
#define HD 128

// ---------------- degree count ----------------
__global__ __launch_bounds__(256) void k_deg(const int* __restrict__ src,
                                             const int* __restrict__ dst,
                                             int* __restrict__ outd,
                                             int* __restrict__ ind) {
    int e = blockIdx.x * 256 + threadIdx.x;
    if (e < NE) {
        atomicAdd(&outd[src[e]], 1);
        atomicAdd(&ind[dst[e]], 1);
    }
}

// ---------------- norms ----------------
__global__ __launch_bounds__(256) void k_norm(const int* __restrict__ outd,
                                              const int* __restrict__ ind,
                                              float* __restrict__ no,
                                              float* __restrict__ ni) {
    int v = blockIdx.x * 256 + threadIdx.x;
    if (v < NN) {
        no[v] = rsqrtf(fmaxf((float)outd[v], 1.0f));
        ni[v] = rsqrtf(fmaxf((float)ind[v], 1.0f));
    }
}

// ---------------- prefix scan of in-degree (3 stages) ----------------
__global__ __launch_bounds__(256) void k_scan1(const int* __restrict__ ind,
                                               int* __restrict__ part,
                                               int* __restrict__ bsum) {
    __shared__ int s[256];
    int i = blockIdx.x * 256 + threadIdx.x;
    int v = (i < NN) ? ind[i] : 0;
    s[threadIdx.x] = v;
    __syncthreads();
    for (int off = 1; off < 256; off <<= 1) {
        int t = (threadIdx.x >= off) ? s[threadIdx.x - off] : 0;
        __syncthreads();
        s[threadIdx.x] += t;
        __syncthreads();
    }
    if (i < NN) part[i] = s[threadIdx.x] - v;  // exclusive within block
    if (threadIdx.x == 255) bsum[blockIdx.x] = s[255];
}

__global__ __launch_bounds__(512) void k_scan2(int* __restrict__ bsum, int nb) {
    __shared__ int s[512];
    int v = (threadIdx.x < nb) ? bsum[threadIdx.x] : 0;
    s[threadIdx.x] = v;
    __syncthreads();
    for (int off = 1; off < 512; off <<= 1) {
        int t = (threadIdx.x >= off) ? s[threadIdx.x - off] : 0;
        __syncthreads();
        s[threadIdx.x] += t;
        __syncthreads();
    }
    if (threadIdx.x < nb) bsum[threadIdx.x] = s[threadIdx.x] - v;  // exclusive
}

__global__ __launch_bounds__(256) void k_scan3(int* __restrict__ offs,
                                               const int* __restrict__ bsum,
                                               int* __restrict__ cursor) {
    int i = blockIdx.x * 256 + threadIdx.x;
    if (i < NN) {
        int o = offs[i] + bsum[i >> 8];
        offs[i] = o;
        cursor[i] = o;
    } else if (i == NN) {
        offs[NN] = NE;
    }
}

// ---------------- CSR fill (by dst) ----------------
__global__ __launch_bounds__(256) void k_fill(const int* __restrict__ src,
                                              const int* __restrict__ dst,
                                              int* __restrict__ cursor,
                                              int* __restrict__ csr) {
    int e = blockIdx.x * 256 + threadIdx.x;
    if (e < NE) {
        int p = atomicAdd(&cursor[dst[e]], 1);
        csr[p] = src[e];
    }
}

// ---------------- dense GEMM: Z = A @ W  (A: nrows x 128, W: 128 x 128) ----------------
// 64-row tile in LDS; 256 threads; each thread computes 8 rows x 4 cols.
__global__ __launch_bounds__(256) void k_gemm(const float* __restrict__ A,
                                              const float* __restrict__ W,
                                              float* __restrict__ Z,
                                              int nrows) {
    __shared__ float4 As[64][33];  // padded: 33 float4 per row
    int row0 = blockIdx.x * 64;
    int tid = threadIdx.x;
    const float4* A4 = (const float4*)A;

    // stage A tile: 64 rows x 32 float4
    for (int i = tid; i < 64 * 32; i += 256) {
        int r = i >> 5, c = i & 31;
        int gr = row0 + r;
        As[r][c] = (gr < nrows) ? A4[gr * 32 + c] : make_float4(0.f, 0.f, 0.f, 0.f);
    }
    __syncthreads();

    int fg = tid & 31;        // 32 col-groups of 4
    int rg = tid >> 5;        // 8 row-groups of 8
    int r0 = rg * 8;

    float acc[8][4];
#pragma unroll
    for (int r = 0; r < 8; r++)
#pragma unroll
        for (int c = 0; c < 4; c++) acc[r][c] = 0.f;

    const float4* W4 = (const float4*)W;
    for (int k = 0; k < 128; k += 4) {
        float4 w0 = W4[(k + 0) * 32 + fg];
        float4 w1 = W4[(k + 1) * 32 + fg];
        float4 w2 = W4[(k + 2) * 32 + fg];
        float4 w3 = W4[(k + 3) * 32 + fg];
#pragma unroll
        for (int r = 0; r < 8; r++) {
            float4 a = As[r0 + r][k >> 2];
            acc[r][0] += a.x * w0.x + a.y * w1.x + a.z * w2.x + a.w * w3.x;
            acc[r][1] += a.x * w0.y + a.y * w1.y + a.z * w2.y + a.w * w3.y;
            acc[r][2] += a.x * w0.z + a.y * w1.z + a.z * w2.z + a.w * w3.z;
            acc[r][3] += a.x * w0.w + a.y * w1.w + a.z * w2.w + a.w * w3.w;
        }
    }

    float4* Z4 = (float4*)Z;
#pragma unroll
    for (int r = 0; r < 8; r++) {
        int gr = row0 + r0 + r;
        if (gr < nrows) {
            float4 o;
            o.x = acc[r][0]; o.y = acc[r][1]; o.z = acc[r][2]; o.w = acc[r][3];
            Z4[gr * 32 + fg] = o;
        }
    }
}

// ---------------- aggregation: h'[v] = relu(ni[v]*sum_u no[u]*z[u] + b) ----------------
// 4 nodes per 128-thread block; 32 lanes per node, float4 per lane.
__global__ __launch_bounds__(128) void k_agg(const float4* __restrict__ Z4,
                                             const int* __restrict__ offs,
                                             const int* __restrict__ csr,
                                             const float* __restrict__ no,
                                             const float* __restrict__ ni,
                                             const float4* __restrict__ b4,
                                             float4* __restrict__ H4) {
    int v = blockIdx.x * 4 + (threadIdx.x >> 5);
    int c = threadIdx.x & 31;
    int s = offs[v];
    int e = offs[v + 1];
    float ax = 0.f, ay = 0.f, az = 0.f, aw = 0.f;
    for (int i = s; i < e; i++) {
        int u = csr[i];
        float nu = no[u];
        float4 zr = Z4[u * 32 + c];
        ax += zr.x * nu;
        ay += zr.y * nu;
        az += zr.z * nu;
        aw += zr.w * nu;
    }
    float niv = ni[v];
    float4 bb = b4[c];
    float4 r;
    r.x = fmaxf(ax * niv + bb.x, 0.f);
    r.y = fmaxf(ay * niv + bb.y, 0.f);
    r.z = fmaxf(az * niv + bb.z, 0.f);
    r.w = fmaxf(aw * niv + bb.w, 0.f);
    H4[v * 32 + c] = r;
}

// ---------------- per-graph readout (node2graph is sorted) ----------------
__global__ __launch_bounds__(128) void k_readout(const float* __restrict__ H,
                                                 const int* __restrict__ n2g,
                                                 float* __restrict__ g) {
    int f = threadIdx.x;
    int v0 = blockIdx.x * 128;
    int vend = v0 + 128;
    if (vend > NN) vend = NN;
    float acc = 0.f;
    int cur = n2g[v0];
    for (int v = v0; v < vend; v++) {
        int gid = n2g[v];
        if (gid != cur) {
            atomicAdd(&g[cur * 128 + f], acc);
            acc = 0.f;
            cur = gid;
        }
        acc += H[v * 128 + f];
    }
    atomicAdd(&g[cur * 128 + f], acc);
}

// ---------------- MLP head: out = relu(g@Wm1+bm1)@Wm2 + bm2 ----------------
__global__ __launch_bounds__(128) void k_head(const float* __restrict__ g,
                                              const float* __restrict__ Wm1,
                                              const float* __restrict__ bm1,
                                              const float* __restrict__ Wm2,
                                              const float* __restrict__ bm2,
                                              float* __restrict__ out) {
    __shared__ float gs[128];
    __shared__ float red[128];
    int gi = blockIdx.x;
    int f = threadIdx.x;
    gs[f] = g[gi * 128 + f];
    __syncthreads();
    float acc = bm1[f];
    for (int k = 0; k < 128; k++) acc += gs[k] * Wm1[k * 128 + f];
    float h1 = fmaxf(acc, 0.f);
    red[f] = h1 * Wm2[f];
    __syncthreads();
    for (int s2 = 64; s2 > 0; s2 >>= 1) {
        if (f < s2) red[f] += red[f + s2];
        __syncthreads();
    }
    if (f == 0) out[gi] = red[0] + bm2[0];
}

extern "C" void kernel_launch(void* const* d_in, const int* in_sizes, int n_in,
                              void* d_out, int out_size, void* d_ws, size_t ws_size,
                              hipStream_t stream) {
    const float* x   = (const float*)d_in[0];
    const int*   src = (const int*)d_in[1];
    const int*   dst = (const int*)d_in[2];
    const int*   n2g = (const int*)d_in[3];
    const float* W0  = (const float*)d_in[4];
    const float* b0  = (const float*)d_in[5];
    const float* W1  = (const float*)d_in[6];
    const float* b1  = (const float*)d_in[7];
    const float* W2  = (const float*)d_in[8];
    const float* b2  = (const float*)d_in[9];
    const float* Wm1 = (const float*)d_in[10];
    const float* bm1 = (const float*)d_in[11];
    const float* Wm2 = (const float*)d_in[12];
    const float* bm2 = (const float*)d_in[13];
    float* out = (float*)d_out;

    char* p = (char*)d_ws;
    auto carve = [&](size_t bytes) -> char* {
        char* r = p;
        p += (bytes + 255) & ~(size_t)255;
        return r;
    };
    float* z      = (float*)carve((size_t)NN * HD * 4);
    float* h      = (float*)carve((size_t)NN * HD * 4);
    float* no     = (float*)carve((size_t)NN * 4);
    float* ni     = (float*)carve((size_t)NN * 4);
    int*   outd   = (int*)carve((size_t)NN * 4);
    int*   ind    = (int*)carve((size_t)NN * 4);
    int*   offs   = (int*)carve((size_t)(NN + 1) * 4);
    int*   cursor = (int*)carve((size_t)NN * 4);
    int*   csr    = (int*)carve((size_t)NE * 4);
    int*   bsum   = (int*)carve((size_t)512 * 4);
    float* g      = (float*)carve((size_t)NG * HD * 4);

    hipMemsetAsync(outd, 0, (size_t)NN * 4, stream);
    hipMemsetAsync(ind, 0, (size_t)NN * 4, stream);
    hipMemsetAsync(g, 0, (size_t)NG * HD * 4, stream);

    k_deg<<<NE / 256, 256, 0, stream>>>(src, dst, outd, ind);
    k_norm<<<(NN + 255) / 256, 256, 0, stream>>>(outd, ind, no, ni);
    k_scan1<<<(NN + 255) / 256, 256, 0, stream>>>(ind, offs, bsum);
    k_scan2<<<1, 512, 0, stream>>>(bsum, (NN + 255) / 256);
    k_scan3<<<(NN + 256) / 256, 256, 0, stream>>>(offs, bsum, cursor);
    k_fill<<<NE / 256, 256, 0, stream>>>(src, dst, cursor, csr);

    int gemm_blocks = (NN + 63) / 64;

    // layer 0
    k_gemm<<<gemm_blocks, 256, 0, stream>>>(x, W0, z, NN);
    k_agg<<<NN / 4, 128, 0, stream>>>((const float4*)z, offs, csr, no, ni,
                                      (const float4*)b0, (float4*)h);
    // layer 1
    k_gemm<<<gemm_blocks, 256, 0, stream>>>(h, W1, z, NN);
    k_agg<<<NN / 4, 128, 0, stream>>>((const float4*)z, offs, csr, no, ni,
                                      (const float4*)b1, (float4*)h);
    // layer 2
    k_gemm<<<gemm_blocks, 256, 0, stream>>>(h, W2, z, NN);
    k_agg<<<NN / 4, 128, 0, stream>>>((const float4*)z, offs, csr, no, ni,
                                      (const float4*)b2, (float4*)h);

    k_readout<<<(NN + 127) / 128, 128, 0, stream>>>(h, n2g, g);
    k_head<<<NG, 128, 0, stream>>>(g, Wm1, bm1, Wm2, bm2, out);
}

// Round 2
// 872.338 us; speedup vs baseline: 1.0838x; 1.0838x over previous
//
#include <hip/hip_runtime.h>

#define NN 100000
#define NE 1600000
#define NG 512
#define HD 128

typedef _Float16 half4 __attribute__((ext_vector_type(4)));

// ---------------- degree count ----------------
__global__ __launch_bounds__(256) void k_deg(const int* __restrict__ src,
                                             const int* __restrict__ dst,
                                             int* __restrict__ outd,
                                             int* __restrict__ ind) {
    int e = blockIdx.x * 256 + threadIdx.x;
    if (e < NE) {
        atomicAdd(&outd[src[e]], 1);
        atomicAdd(&ind[dst[e]], 1);
    }
}

// ---------------- norms ----------------
__global__ __launch_bounds__(256) void k_norm(const int* __restrict__ outd,
                                              const int* __restrict__ ind,
                                              float* __restrict__ no,
                                              float* __restrict__ ni) {
    int v = blockIdx.x * 256 + threadIdx.x;
    if (v < NN) {
        no[v] = rsqrtf(fmaxf((float)outd[v], 1.0f));
        ni[v] = rsqrtf(fmaxf((float)ind[v], 1.0f));
    }
}

// ---------------- prefix scan of in-degree (3 stages) ----------------
__global__ __launch_bounds__(256) void k_scan1(const int* __restrict__ ind,
                                               int* __restrict__ part,
                                               int* __restrict__ bsum) {
    __shared__ int s[256];
    int i = blockIdx.x * 256 + threadIdx.x;
    int v = (i < NN) ? ind[i] : 0;
    s[threadIdx.x] = v;
    __syncthreads();
    for (int off = 1; off < 256; off <<= 1) {
        int t = (threadIdx.x >= off) ? s[threadIdx.x - off] : 0;
        __syncthreads();
        s[threadIdx.x] += t;
        __syncthreads();
    }
    if (i < NN) part[i] = s[threadIdx.x] - v;  // exclusive within block
    if (threadIdx.x == 255) bsum[blockIdx.x] = s[255];
}

__global__ __launch_bounds__(512) void k_scan2(int* __restrict__ bsum, int nb) {
    __shared__ int s[512];
    int v = (threadIdx.x < nb) ? bsum[threadIdx.x] : 0;
    s[threadIdx.x] = v;
    __syncthreads();
    for (int off = 1; off < 512; off <<= 1) {
        int t = (threadIdx.x >= off) ? s[threadIdx.x - off] : 0;
        __syncthreads();
        s[threadIdx.x] += t;
        __syncthreads();
    }
    if (threadIdx.x < nb) bsum[threadIdx.x] = s[threadIdx.x] - v;  // exclusive
}

__global__ __launch_bounds__(256) void k_scan3(int* __restrict__ offs,
                                               const int* __restrict__ bsum,
                                               int* __restrict__ cursor) {
    int i = blockIdx.x * 256 + threadIdx.x;
    if (i < NN) {
        int o = offs[i] + bsum[i >> 8];
        offs[i] = o;
        cursor[i] = o;
    } else if (i == NN) {
        offs[NN] = NE;
    }
}

// ---------------- CSR fill (by dst) ----------------
__global__ __launch_bounds__(256) void k_fill(const int* __restrict__ src,
                                              const int* __restrict__ dst,
                                              int* __restrict__ cursor,
                                              int* __restrict__ csr) {
    int e = blockIdx.x * 256 + threadIdx.x;
    if (e < NE) {
        int p = atomicAdd(&cursor[dst[e]], 1);
        csr[p] = src[e];
    }
}

// ---------------- dense GEMM: Z = no[row] * (A @ W), fp32 compute, fp16 out ----------------
// 64-row tile in LDS; 256 threads; each thread computes 8 rows x 4 cols.
__global__ __launch_bounds__(256) void k_gemm(const float* __restrict__ A,
                                              const float* __restrict__ W,
                                              const float* __restrict__ no,
                                              half4* __restrict__ Zh,
                                              int nrows) {
    __shared__ float4 As[64][33];  // padded: 33 float4 per row
    int row0 = blockIdx.x * 64;
    int tid = threadIdx.x;
    const float4* A4 = (const float4*)A;

    // stage A tile: 64 rows x 32 float4
    for (int i = tid; i < 64 * 32; i += 256) {
        int r = i >> 5, c = i & 31;
        int gr = row0 + r;
        As[r][c] = (gr < nrows) ? A4[gr * 32 + c] : make_float4(0.f, 0.f, 0.f, 0.f);
    }
    __syncthreads();

    int fg = tid & 31;        // 32 col-groups of 4
    int rg = tid >> 5;        // 8 row-groups of 8
    int r0 = rg * 8;

    float acc[8][4];
#pragma unroll
    for (int r = 0; r < 8; r++)
#pragma unroll
        for (int c = 0; c < 4; c++) acc[r][c] = 0.f;

    const float4* W4 = (const float4*)W;
    for (int k = 0; k < 128; k += 4) {
        float4 w0 = W4[(k + 0) * 32 + fg];
        float4 w1 = W4[(k + 1) * 32 + fg];
        float4 w2 = W4[(k + 2) * 32 + fg];
        float4 w3 = W4[(k + 3) * 32 + fg];
#pragma unroll
        for (int r = 0; r < 8; r++) {
            float4 a = As[r0 + r][k >> 2];
            acc[r][0] += a.x * w0.x + a.y * w1.x + a.z * w2.x + a.w * w3.x;
            acc[r][1] += a.x * w0.y + a.y * w1.y + a.z * w2.y + a.w * w3.y;
            acc[r][2] += a.x * w0.z + a.y * w1.z + a.z * w2.z + a.w * w3.z;
            acc[r][3] += a.x * w0.w + a.y * w1.w + a.z * w2.w + a.w * w3.w;
        }
    }

#pragma unroll
    for (int r = 0; r < 8; r++) {
        int gr = row0 + r0 + r;
        if (gr < nrows) {
            float nov = no[gr];
            half4 o;
            o.x = (_Float16)(acc[r][0] * nov);
            o.y = (_Float16)(acc[r][1] * nov);
            o.z = (_Float16)(acc[r][2] * nov);
            o.w = (_Float16)(acc[r][3] * nov);
            Zh[gr * 32 + fg] = o;
        }
    }
}

// ---------------- aggregation: h'[v] = relu(ni[v]*sum_u zh[u] + b) ----------------
// 4 nodes per 128-thread block; 32 lanes per node, half4 (8 B) per lane.
__global__ __launch_bounds__(128) void k_agg(const half4* __restrict__ Zh,
                                             const int* __restrict__ offs,
                                             const int* __restrict__ csr,
                                             const float* __restrict__ ni,
                                             const float4* __restrict__ b4,
                                             float4* __restrict__ H4) {
    int v = blockIdx.x * 4 + (threadIdx.x >> 5);
    int c = threadIdx.x & 31;
    int s = offs[v];
    int e = offs[v + 1];
    float ax = 0.f, ay = 0.f, az = 0.f, aw = 0.f;
    int u = (s < e) ? csr[s] : 0;
    for (int i = s; i < e; i++) {
        int unext = (i + 1 < e) ? csr[i + 1] : 0;
        half4 zr = Zh[u * 32 + c];
        ax += (float)zr.x;
        ay += (float)zr.y;
        az += (float)zr.z;
        aw += (float)zr.w;
        u = unext;
    }
    float niv = ni[v];
    float4 bb = b4[c];
    float4 r;
    r.x = fmaxf(ax * niv + bb.x, 0.f);
    r.y = fmaxf(ay * niv + bb.y, 0.f);
    r.z = fmaxf(az * niv + bb.z, 0.f);
    r.w = fmaxf(aw * niv + bb.w, 0.f);
    H4[v * 32 + c] = r;
}

// ---------------- per-graph readout (node2graph is sorted) ----------------
__global__ __launch_bounds__(128) void k_readout(const float* __restrict__ H,
                                                 const int* __restrict__ n2g,
                                                 float* __restrict__ g) {
    int f = threadIdx.x;
    int v0 = blockIdx.x * 128;
    int vend = v0 + 128;
    if (vend > NN) vend = NN;
    float acc = 0.f;
    int cur = n2g[v0];
    for (int v = v0; v < vend; v++) {
        int gid = n2g[v];
        if (gid != cur) {
            atomicAdd(&g[cur * 128 + f], acc);
            acc = 0.f;
            cur = gid;
        }
        acc += H[v * 128 + f];
    }
    atomicAdd(&g[cur * 128 + f], acc);
}

// ---------------- MLP head: out = relu(g@Wm1+bm1)@Wm2 + bm2 ----------------
__global__ __launch_bounds__(128) void k_head(const float* __restrict__ g,
                                              const float* __restrict__ Wm1,
                                              const float* __restrict__ bm1,
                                              const float* __restrict__ Wm2,
                                              const float* __restrict__ bm2,
                                              float* __restrict__ out) {
    __shared__ float gs[128];
    __shared__ float red[128];
    int gi = blockIdx.x;
    int f = threadIdx.x;
    gs[f] = g[gi * 128 + f];
    __syncthreads();
    float acc = bm1[f];
    for (int k = 0; k < 128; k++) acc += gs[k] * Wm1[k * 128 + f];
    float h1 = fmaxf(acc, 0.f);
    red[f] = h1 * Wm2[f];
    __syncthreads();
    for (int s2 = 64; s2 > 0; s2 >>= 1) {
        if (f < s2) red[f] += red[f + s2];
        __syncthreads();
    }
    if (f == 0) out[gi] = red[0] + bm2[0];
}

extern "C" void kernel_launch(void* const* d_in, const int* in_sizes, int n_in,
                              void* d_out, int out_size, void* d_ws, size_t ws_size,
                              hipStream_t stream) {
    const float* x   = (const float*)d_in[0];
    const int*   src = (const int*)d_in[1];
    const int*   dst = (const int*)d_in[2];
    const int*   n2g = (const int*)d_in[3];
    const float* W0  = (const float*)d_in[4];
    const float* b0  = (const float*)d_in[5];
    const float* W1  = (const float*)d_in[6];
    const float* b1  = (const float*)d_in[7];
    const float* W2  = (const float*)d_in[8];
    const float* b2  = (const float*)d_in[9];
    const float* Wm1 = (const float*)d_in[10];
    const float* bm1 = (const float*)d_in[11];
    const float* Wm2 = (const float*)d_in[12];
    const float* bm2 = (const float*)d_in[13];
    float* out = (float*)d_out;

    char* p = (char*)d_ws;
    auto carve = [&](size_t bytes) -> char* {
        char* r = p;
        p += (bytes + 255) & ~(size_t)255;
        return r;
    };
    half4* zh     = (half4*)carve((size_t)NN * HD * 2);
    float* h      = (float*)carve((size_t)NN * HD * 4);
    float* no     = (float*)carve((size_t)NN * 4);
    float* ni     = (float*)carve((size_t)NN * 4);
    int*   outd   = (int*)carve((size_t)NN * 4);
    int*   ind    = (int*)carve((size_t)NN * 4);
    int*   offs   = (int*)carve((size_t)(NN + 1) * 4);
    int*   cursor = (int*)carve((size_t)NN * 4);
    int*   csr    = (int*)carve((size_t)NE * 4);
    int*   bsum   = (int*)carve((size_t)512 * 4);
    float* g      = (float*)carve((size_t)NG * HD * 4);

    hipMemsetAsync(outd, 0, (size_t)NN * 4, stream);
    hipMemsetAsync(ind, 0, (size_t)NN * 4, stream);
    hipMemsetAsync(g, 0, (size_t)NG * HD * 4, stream);

    k_deg<<<NE / 256, 256, 0, stream>>>(src, dst, outd, ind);
    k_norm<<<(NN + 255) / 256, 256, 0, stream>>>(outd, ind, no, ni);
    k_scan1<<<(NN + 255) / 256, 256, 0, stream>>>(ind, offs, bsum);
    k_scan2<<<1, 512, 0, stream>>>(bsum, (NN + 255) / 256);
    k_scan3<<<(NN + 256) / 256, 256, 0, stream>>>(offs, bsum, cursor);
    k_fill<<<NE / 256, 256, 0, stream>>>(src, dst, cursor, csr);

    int gemm_blocks = (NN + 63) / 64;

    // layer 0
    k_gemm<<<gemm_blocks, 256, 0, stream>>>(x, W0, no, zh, NN);
    k_agg<<<NN / 4, 128, 0, stream>>>(zh, offs, csr, ni, (const float4*)b0, (float4*)h);
    // layer 1
    k_gemm<<<gemm_blocks, 256, 0, stream>>>(h, W1, no, zh, NN);
    k_agg<<<NN / 4, 128, 0, stream>>>(zh, offs, csr, ni, (const float4*)b1, (float4*)h);
    // layer 2
    k_gemm<<<gemm_blocks, 256, 0, stream>>>(h, W2, no, zh, NN);
    k_agg<<<NN / 4, 128, 0, stream>>>(zh, offs, csr, ni, (const float4*)b2, (float4*)h);

    k_readout<<<(NN + 127) / 128, 128, 0, stream>>>(h, n2g, g);
    k_head<<<NG, 128, 0, stream>>>(g, Wm1, bm1, Wm2, bm2, out);
}

// Round 3
// 687.013 us; speedup vs baseline: 1.3762x; 1.2698x over previous
//
#include <hip/hip_runtime.h>

#define NN 100000
#define NE 1600000
#define NG 512
#define HD 128

#define NBK 196            // node buckets of 512: 196*512 = 100352 >= NN
#define CHUNK 5120         // edges per chunk
#define NC 313             // ceil(NE/CHUNK)
#define LH (2 * NBK * NC)  // 122696 histogram entries (dst part | src part)

typedef _Float16 half4 __attribute__((ext_vector_type(4)));

// ---------------- pass A1: per-chunk bucket histograms (dst and src) ----------------
__global__ __launch_bounds__(256) void k_hist(const int* __restrict__ src,
                                              const int* __restrict__ dst,
                                              int* __restrict__ H) {
    __shared__ int hd[NBK], hs[NBK];
    int c = blockIdx.x;
    for (int i = threadIdx.x; i < NBK; i += 256) { hd[i] = 0; hs[i] = 0; }
    __syncthreads();
    int e0 = c * CHUNK;
    int e1 = e0 + CHUNK; if (e1 > NE) e1 = NE;
    for (int e = e0 + threadIdx.x; e < e1; e += 256) {
        atomicAdd(&hd[dst[e] >> 9], 1);
        atomicAdd(&hs[src[e] >> 9], 1);
    }
    __syncthreads();
    for (int i = threadIdx.x; i < NBK; i += 256) {
        H[i * NC + c] = hd[i];
        H[NBK * NC + i * NC + c] = hs[i];
    }
}

// ---------------- generic 3-stage exclusive scan ----------------
__global__ __launch_bounds__(256) void k_scan1g(int* __restrict__ H,
                                                int* __restrict__ bsum, int L) {
    __shared__ int s[256];
    int i = blockIdx.x * 256 + threadIdx.x;
    int v = (i < L) ? H[i] : 0;
    s[threadIdx.x] = v;
    __syncthreads();
    for (int off = 1; off < 256; off <<= 1) {
        int t = (threadIdx.x >= off) ? s[threadIdx.x - off] : 0;
        __syncthreads();
        s[threadIdx.x] += t;
        __syncthreads();
    }
    if (i < L) H[i] = s[threadIdx.x] - v;
    if (threadIdx.x == 255) bsum[blockIdx.x] = s[255];
}

__global__ __launch_bounds__(512) void k_scan2(int* __restrict__ bsum, int nb) {
    __shared__ int s[512];
    int v = (threadIdx.x < nb) ? bsum[threadIdx.x] : 0;
    s[threadIdx.x] = v;
    __syncthreads();
    for (int off = 1; off < 512; off <<= 1) {
        int t = (threadIdx.x >= off) ? s[threadIdx.x - off] : 0;
        __syncthreads();
        s[threadIdx.x] += t;
        __syncthreads();
    }
    if (threadIdx.x < nb) bsum[threadIdx.x] = s[threadIdx.x] - v;
}

__global__ __launch_bounds__(256) void k_scan3g(int* __restrict__ H,
                                                const int* __restrict__ bsum, int L) {
    int i = blockIdx.x * 256 + threadIdx.x;
    if (i < L) H[i] += bsum[i >> 8];
}

// ---------------- pass A2: partition edges into buckets ----------------
__global__ __launch_bounds__(256) void k_scatter(const int* __restrict__ src,
                                                 const int* __restrict__ dst,
                                                 const int* __restrict__ H,
                                                 int2* __restrict__ dpart,
                                                 int* __restrict__ spart) {
    __shared__ int cd[NBK], cs[NBK];
    int c = blockIdx.x;
    for (int i = threadIdx.x; i < NBK; i += 256) {
        cd[i] = H[i * NC + c];
        cs[i] = H[NBK * NC + i * NC + c] - NE;
    }
    __syncthreads();
    int e0 = c * CHUNK;
    int e1 = e0 + CHUNK; if (e1 > NE) e1 = NE;
    for (int e = e0 + threadIdx.x; e < e1; e += 256) {
        int s = src[e], d = dst[e];
        int pd = atomicAdd(&cd[d >> 9], 1);
        dpart[pd] = make_int2(s, d);
        int ps = atomicAdd(&cs[s >> 9], 1);
        spart[ps] = s;
    }
}

// ---------------- pass B: per-bucket degree count, offs, norms, CSR fill ----------------
__global__ __launch_bounds__(256) void k_bucket(const int2* __restrict__ dpart,
                                                const int* __restrict__ spart,
                                                const int* __restrict__ H,
                                                int* __restrict__ offs,
                                                int* __restrict__ csr,
                                                float* __restrict__ ni,
                                                float* __restrict__ no) {
    __shared__ int deg[512];
    __shared__ int cur[512];
    __shared__ int tmp[256];
    int b = blockIdx.x;
    bool isDst = (b < NBK);
    int bb = isDst ? b : b - NBK;
    int start, end;
    if (isDst) {
        start = H[bb * NC];
        end = (bb + 1 < NBK) ? H[(bb + 1) * NC] : NE;
    } else {
        start = H[NBK * NC + bb * NC] - NE;
        end = (bb + 1 < NBK) ? H[NBK * NC + (bb + 1) * NC] - NE : NE;
    }
    for (int i = threadIdx.x; i < 512; i += 256) deg[i] = 0;
    __syncthreads();
    if (isDst) {
        for (int i = start + threadIdx.x; i < end; i += 256)
            atomicAdd(&deg[dpart[i].y & 511], 1);
    } else {
        for (int i = start + threadIdx.x; i < end; i += 256)
            atomicAdd(&deg[spart[i] & 511], 1);
    }
    __syncthreads();
    int vb = bb * 512;
    if (!isDst) {
        // out-degree -> norm_out only
        for (int i = threadIdx.x; i < 512; i += 256) {
            int v = vb + i;
            if (v < NN) no[v] = rsqrtf(fmaxf((float)deg[i], 1.0f));
        }
        return;
    }
    // exclusive scan of deg[512] with 256 threads (pair + Hillis-Steele)
    int t = threadIdx.x;
    int a0 = deg[2 * t], a1 = deg[2 * t + 1];
    int pair = a0 + a1;
    tmp[t] = pair;
    __syncthreads();
    for (int off = 1; off < 256; off <<= 1) {
        int v2 = (t >= off) ? tmp[t - off] : 0;
        __syncthreads();
        tmp[t] += v2;
        __syncthreads();
    }
    int ex = tmp[t] - pair;
    cur[2 * t] = start + ex;
    cur[2 * t + 1] = start + ex + a0;
    __syncthreads();
    for (int i = threadIdx.x; i < 512; i += 256) {
        int v = vb + i;
        if (v < NN) {
            offs[v] = cur[i];
            ni[v] = rsqrtf(fmaxf((float)deg[i], 1.0f));
        }
    }
    if (b == NBK - 1 && threadIdx.x == 0) offs[NN] = NE;
    __syncthreads();
    for (int i = start + threadIdx.x; i < end; i += 256) {
        int2 e = dpart[i];
        int p = atomicAdd(&cur[e.y & 511], 1);
        csr[p] = e.x;
    }
}

// ---------------- dense GEMM: Z = no[row] * (A @ W), fp32 compute, fp16 out ----------------
__global__ __launch_bounds__(256) void k_gemm(const float* __restrict__ A,
                                              const float* __restrict__ W,
                                              const float* __restrict__ no,
                                              half4* __restrict__ Zh,
                                              int nrows) {
    __shared__ float4 As[64][33];
    int row0 = blockIdx.x * 64;
    int tid = threadIdx.x;
    const float4* A4 = (const float4*)A;

    for (int i = tid; i < 64 * 32; i += 256) {
        int r = i >> 5, c = i & 31;
        int gr = row0 + r;
        As[r][c] = (gr < nrows) ? A4[gr * 32 + c] : make_float4(0.f, 0.f, 0.f, 0.f);
    }
    __syncthreads();

    int fg = tid & 31;
    int rg = tid >> 5;
    int r0 = rg * 8;

    float acc[8][4];
#pragma unroll
    for (int r = 0; r < 8; r++)
#pragma unroll
        for (int c = 0; c < 4; c++) acc[r][c] = 0.f;

    const float4* W4 = (const float4*)W;
    for (int k = 0; k < 128; k += 4) {
        float4 w0 = W4[(k + 0) * 32 + fg];
        float4 w1 = W4[(k + 1) * 32 + fg];
        float4 w2 = W4[(k + 2) * 32 + fg];
        float4 w3 = W4[(k + 3) * 32 + fg];
#pragma unroll
        for (int r = 0; r < 8; r++) {
            float4 a = As[r0 + r][k >> 2];
            acc[r][0] += a.x * w0.x + a.y * w1.x + a.z * w2.x + a.w * w3.x;
            acc[r][1] += a.x * w0.y + a.y * w1.y + a.z * w2.y + a.w * w3.y;
            acc[r][2] += a.x * w0.z + a.y * w1.z + a.z * w2.z + a.w * w3.z;
            acc[r][3] += a.x * w0.w + a.y * w1.w + a.z * w2.w + a.w * w3.w;
        }
    }

#pragma unroll
    for (int r = 0; r < 8; r++) {
        int gr = row0 + r0 + r;
        if (gr < nrows) {
            float nov = no[gr];
            half4 o;
            o.x = (_Float16)(acc[r][0] * nov);
            o.y = (_Float16)(acc[r][1] * nov);
            o.z = (_Float16)(acc[r][2] * nov);
            o.w = (_Float16)(acc[r][3] * nov);
            Zh[gr * 32 + fg] = o;
        }
    }
}

// ---------------- aggregation: h'[v] = relu(ni[v]*sum_u zh[u] + b) ----------------
__global__ __launch_bounds__(128) void k_agg(const half4* __restrict__ Zh,
                                             const int* __restrict__ offs,
                                             const int* __restrict__ csr,
                                             const float* __restrict__ ni,
                                             const float4* __restrict__ b4,
                                             float4* __restrict__ H4) {
    int v = blockIdx.x * 4 + (threadIdx.x >> 5);
    int c = threadIdx.x & 31;
    int s = offs[v];
    int e = offs[v + 1];
    float ax = 0.f, ay = 0.f, az = 0.f, aw = 0.f;
    int u = (s < e) ? csr[s] : 0;
    for (int i = s; i < e; i++) {
        int unext = (i + 1 < e) ? csr[i + 1] : 0;
        half4 zr = Zh[u * 32 + c];
        ax += (float)zr.x;
        ay += (float)zr.y;
        az += (float)zr.z;
        aw += (float)zr.w;
        u = unext;
    }
    float niv = ni[v];
    float4 bb = b4[c];
    float4 r;
    r.x = fmaxf(ax * niv + bb.x, 0.f);
    r.y = fmaxf(ay * niv + bb.y, 0.f);
    r.z = fmaxf(az * niv + bb.z, 0.f);
    r.w = fmaxf(aw * niv + bb.w, 0.f);
    H4[v * 32 + c] = r;
}

// ---------------- per-graph readout (node2graph is sorted) ----------------
__global__ __launch_bounds__(128) void k_readout(const float* __restrict__ H,
                                                 const int* __restrict__ n2g,
                                                 float* __restrict__ g) {
    int f = threadIdx.x;
    int v0 = blockIdx.x * 128;
    int vend = v0 + 128;
    if (vend > NN) vend = NN;
    float acc = 0.f;
    int cur = n2g[v0];
    for (int v = v0; v < vend; v++) {
        int gid = n2g[v];
        if (gid != cur) {
            atomicAdd(&g[cur * 128 + f], acc);
            acc = 0.f;
            cur = gid;
        }
        acc += H[v * 128 + f];
    }
    atomicAdd(&g[cur * 128 + f], acc);
}

// ---------------- MLP head: out = relu(g@Wm1+bm1)@Wm2 + bm2 ----------------
__global__ __launch_bounds__(128) void k_head(const float* __restrict__ g,
                                              const float* __restrict__ Wm1,
                                              const float* __restrict__ bm1,
                                              const float* __restrict__ Wm2,
                                              const float* __restrict__ bm2,
                                              float* __restrict__ out) {
    __shared__ float gs[128];
    __shared__ float red[128];
    int gi = blockIdx.x;
    int f = threadIdx.x;
    gs[f] = g[gi * 128 + f];
    __syncthreads();
    float acc = bm1[f];
    for (int k = 0; k < 128; k++) acc += gs[k] * Wm1[k * 128 + f];
    float h1 = fmaxf(acc, 0.f);
    red[f] = h1 * Wm2[f];
    __syncthreads();
    for (int s2 = 64; s2 > 0; s2 >>= 1) {
        if (f < s2) red[f] += red[f + s2];
        __syncthreads();
    }
    if (f == 0) out[gi] = red[0] + bm2[0];
}

extern "C" void kernel_launch(void* const* d_in, const int* in_sizes, int n_in,
                              void* d_out, int out_size, void* d_ws, size_t ws_size,
                              hipStream_t stream) {
    const float* x   = (const float*)d_in[0];
    const int*   src = (const int*)d_in[1];
    const int*   dst = (const int*)d_in[2];
    const int*   n2g = (const int*)d_in[3];
    const float* W0  = (const float*)d_in[4];
    const float* b0  = (const float*)d_in[5];
    const float* W1  = (const float*)d_in[6];
    const float* b1  = (const float*)d_in[7];
    const float* W2  = (const float*)d_in[8];
    const float* b2  = (const float*)d_in[9];
    const float* Wm1 = (const float*)d_in[10];
    const float* bm1 = (const float*)d_in[11];
    const float* Wm2 = (const float*)d_in[12];
    const float* bm2 = (const float*)d_in[13];
    float* out = (float*)d_out;

    char* p = (char*)d_ws;
    auto carve = [&](size_t bytes) -> char* {
        char* r = p;
        p += (bytes + 255) & ~(size_t)255;
        return r;
    };
    half4* zh     = (half4*)carve((size_t)NN * HD * 2);
    float* h      = (float*)carve((size_t)NN * HD * 4);
    float* no     = (float*)carve((size_t)NN * 4);
    float* ni     = (float*)carve((size_t)NN * 4);
    int*   offs   = (int*)carve((size_t)(NN + 1) * 4);
    int*   csr    = (int*)carve((size_t)NE * 4);
    int*   Hh     = (int*)carve((size_t)LH * 4);
    int*   bsum   = (int*)carve((size_t)512 * 4);
    int2*  dpart  = (int2*)carve((size_t)NE * 8);
    int*   spart  = (int*)carve((size_t)NE * 4);
    float* g      = (float*)carve((size_t)NG * HD * 4);

    hipMemsetAsync(g, 0, (size_t)NG * HD * 4, stream);

    // graph build: bucketed counting sort (LDS atomics, contained writes)
    int scan_blocks = (LH + 255) / 256;  // 480 <= 512
    k_hist<<<NC, 256, 0, stream>>>(src, dst, Hh);
    k_scan1g<<<scan_blocks, 256, 0, stream>>>(Hh, bsum, LH);
    k_scan2<<<1, 512, 0, stream>>>(bsum, scan_blocks);
    k_scan3g<<<scan_blocks, 256, 0, stream>>>(Hh, bsum, LH);
    k_scatter<<<NC, 256, 0, stream>>>(src, dst, Hh, dpart, spart);
    k_bucket<<<2 * NBK, 256, 0, stream>>>(dpart, spart, Hh, offs, csr, ni, no);

    int gemm_blocks = (NN + 63) / 64;

    // layer 0
    k_gemm<<<gemm_blocks, 256, 0, stream>>>(x, W0, no, zh, NN);
    k_agg<<<NN / 4, 128, 0, stream>>>(zh, offs, csr, ni, (const float4*)b0, (float4*)h);
    // layer 1
    k_gemm<<<gemm_blocks, 256, 0, stream>>>(h, W1, no, zh, NN);
    k_agg<<<NN / 4, 128, 0, stream>>>(zh, offs, csr, ni, (const float4*)b1, (float4*)h);
    // layer 2
    k_gemm<<<gemm_blocks, 256, 0, stream>>>(h, W2, no, zh, NN);
    k_agg<<<NN / 4, 128, 0, stream>>>(zh, offs, csr, ni, (const float4*)b2, (float4*)h);

    k_readout<<<(NN + 127) / 128, 128, 0, stream>>>(h, n2g, g);
    k_head<<<NG, 128, 0, stream>>>(g, Wm1, bm1, Wm2, bm2, out);
}

// Round 4
// 657.018 us; speedup vs baseline: 1.4390x; 1.0457x over previous
//
#include <hip/hip_runtime.h>

#define NN 100000
#define NE 1600000
#define NG 512
#define HD 128

#define NBK 196            // node buckets of 512: 196*512 = 100352 >= NN
#define CHUNK 5120         // edges per chunk
#define NC 313             // ceil(NE/CHUNK)
#define LH (2 * NBK * NC)  // 122696 histogram entries (dst part | src part)

typedef _Float16 half4 __attribute__((ext_vector_type(4)));

// ---------------- pass A1: per-chunk bucket histograms (dst and src) ----------------
__global__ __launch_bounds__(256) void k_hist(const int* __restrict__ src,
                                              const int* __restrict__ dst,
                                              int* __restrict__ H) {
    __shared__ int hd[NBK], hs[NBK];
    int c = blockIdx.x;
    for (int i = threadIdx.x; i < NBK; i += 256) { hd[i] = 0; hs[i] = 0; }
    __syncthreads();
    int e0 = c * CHUNK;
    int e1 = e0 + CHUNK; if (e1 > NE) e1 = NE;
    for (int e = e0 + threadIdx.x; e < e1; e += 256) {
        atomicAdd(&hd[dst[e] >> 9], 1);
        atomicAdd(&hs[src[e] >> 9], 1);
    }
    __syncthreads();
    for (int i = threadIdx.x; i < NBK; i += 256) {
        H[i * NC + c] = hd[i];
        H[NBK * NC + i * NC + c] = hs[i];
    }
}

// ---------------- generic 3-stage exclusive scan ----------------
__global__ __launch_bounds__(256) void k_scan1g(int* __restrict__ H,
                                                int* __restrict__ bsum, int L) {
    __shared__ int s[256];
    int i = blockIdx.x * 256 + threadIdx.x;
    int v = (i < L) ? H[i] : 0;
    s[threadIdx.x] = v;
    __syncthreads();
    for (int off = 1; off < 256; off <<= 1) {
        int t = (threadIdx.x >= off) ? s[threadIdx.x - off] : 0;
        __syncthreads();
        s[threadIdx.x] += t;
        __syncthreads();
    }
    if (i < L) H[i] = s[threadIdx.x] - v;
    if (threadIdx.x == 255) bsum[blockIdx.x] = s[255];
}

__global__ __launch_bounds__(512) void k_scan2(int* __restrict__ bsum, int nb) {
    __shared__ int s[512];
    int v = (threadIdx.x < nb) ? bsum[threadIdx.x] : 0;
    s[threadIdx.x] = v;
    __syncthreads();
    for (int off = 1; off < 512; off <<= 1) {
        int t = (threadIdx.x >= off) ? s[threadIdx.x - off] : 0;
        __syncthreads();
        s[threadIdx.x] += t;
        __syncthreads();
    }
    if (threadIdx.x < nb) bsum[threadIdx.x] = s[threadIdx.x] - v;
}

__global__ __launch_bounds__(256) void k_scan3g(int* __restrict__ H,
                                                const int* __restrict__ bsum, int L) {
    int i = blockIdx.x * 256 + threadIdx.x;
    if (i < L) H[i] += bsum[i >> 8];
}

// ---------------- pass A2: partition edges into buckets ----------------
__global__ __launch_bounds__(256) void k_scatter(const int* __restrict__ src,
                                                 const int* __restrict__ dst,
                                                 const int* __restrict__ H,
                                                 int2* __restrict__ dpart,
                                                 int* __restrict__ spart) {
    __shared__ int cd[NBK], cs[NBK];
    int c = blockIdx.x;
    for (int i = threadIdx.x; i < NBK; i += 256) {
        cd[i] = H[i * NC + c];
        cs[i] = H[NBK * NC + i * NC + c] - NE;
    }
    __syncthreads();
    int e0 = c * CHUNK;
    int e1 = e0 + CHUNK; if (e1 > NE) e1 = NE;
    for (int e = e0 + threadIdx.x; e < e1; e += 256) {
        int s = src[e], d = dst[e];
        int pd = atomicAdd(&cd[d >> 9], 1);
        dpart[pd] = make_int2(s, d);
        int ps = atomicAdd(&cs[s >> 9], 1);
        spart[ps] = s;
    }
}

// ---------------- pass B: per-bucket degree count, offs, norms, CSR fill ----------------
__global__ __launch_bounds__(256) void k_bucket(const int2* __restrict__ dpart,
                                                const int* __restrict__ spart,
                                                const int* __restrict__ H,
                                                int* __restrict__ offs,
                                                int* __restrict__ csr,
                                                float* __restrict__ ni,
                                                float* __restrict__ no) {
    __shared__ int deg[512];
    __shared__ int cur[512];
    __shared__ int tmp[256];
    int b = blockIdx.x;
    bool isDst = (b < NBK);
    int bb = isDst ? b : b - NBK;
    int start, end;
    if (isDst) {
        start = H[bb * NC];
        end = (bb + 1 < NBK) ? H[(bb + 1) * NC] : NE;
    } else {
        start = H[NBK * NC + bb * NC] - NE;
        end = (bb + 1 < NBK) ? H[NBK * NC + (bb + 1) * NC] - NE : NE;
    }
    for (int i = threadIdx.x; i < 512; i += 256) deg[i] = 0;
    __syncthreads();
    if (isDst) {
        for (int i = start + threadIdx.x; i < end; i += 256)
            atomicAdd(&deg[dpart[i].y & 511], 1);
    } else {
        for (int i = start + threadIdx.x; i < end; i += 256)
            atomicAdd(&deg[spart[i] & 511], 1);
    }
    __syncthreads();
    int vb = bb * 512;
    if (!isDst) {
        for (int i = threadIdx.x; i < 512; i += 256) {
            int v = vb + i;
            if (v < NN) no[v] = rsqrtf(fmaxf((float)deg[i], 1.0f));
        }
        return;
    }
    // exclusive scan of deg[512] with 256 threads
    int t = threadIdx.x;
    int a0 = deg[2 * t], a1 = deg[2 * t + 1];
    int pair = a0 + a1;
    tmp[t] = pair;
    __syncthreads();
    for (int off = 1; off < 256; off <<= 1) {
        int v2 = (t >= off) ? tmp[t - off] : 0;
        __syncthreads();
        tmp[t] += v2;
        __syncthreads();
    }
    int ex = tmp[t] - pair;
    cur[2 * t] = start + ex;
    cur[2 * t + 1] = start + ex + a0;
    __syncthreads();
    for (int i = threadIdx.x; i < 512; i += 256) {
        int v = vb + i;
        if (v < NN) {
            offs[v] = cur[i];
            ni[v] = rsqrtf(fmaxf((float)deg[i], 1.0f));
        }
    }
    if (b == NBK - 1 && threadIdx.x == 0) offs[NN] = NE;
    __syncthreads();
    for (int i = start + threadIdx.x; i < end; i += 256) {
        int2 e = dpart[i];
        int p = atomicAdd(&cur[e.y & 511], 1);
        csr[p] = e.x;
    }
}

// ---------------- dense GEMM: Z = no[row] * (A @ W), fp32 compute, fp16 out ----------------
// 128-row tile (64 KB LDS), 256 threads, each thread 16 rows x 4 cols.
// W loads register-prefetched; each W load feeds 256 FMAs.
__global__ __launch_bounds__(256) void k_gemm(const float* __restrict__ A,
                                              const float* __restrict__ W,
                                              const float* __restrict__ no,
                                              half4* __restrict__ Zh,
                                              int nrows) {
    __shared__ float4 As[128][32];  // 64 KB exactly; tile reads are wave-broadcast
    int row0 = blockIdx.x * 128;
    int tid = threadIdx.x;
    const float4* A4 = (const float4*)A;

    for (int i = tid; i < 128 * 32; i += 256) {
        int r = i >> 5, c = i & 31;
        int gr = row0 + r;
        As[r][c] = (gr < nrows) ? A4[gr * 32 + c] : make_float4(0.f, 0.f, 0.f, 0.f);
    }
    __syncthreads();

    int fg = tid & 31;        // 32 col-groups of 4
    int rg = tid >> 5;        // 8 row-groups of 16
    int r0 = rg * 16;

    float acc[16][4];
#pragma unroll
    for (int r = 0; r < 16; r++)
#pragma unroll
        for (int c = 0; c < 4; c++) acc[r][c] = 0.f;

    const float4* W4 = (const float4*)W;
    float4 w0 = W4[0 * 32 + fg];
    float4 w1 = W4[1 * 32 + fg];
    float4 w2 = W4[2 * 32 + fg];
    float4 w3 = W4[3 * 32 + fg];
    for (int k = 0; k < 128; k += 4) {
        float4 nw0, nw1, nw2, nw3;
        if (k + 4 < 128) {
            nw0 = W4[(k + 4) * 32 + fg];
            nw1 = W4[(k + 5) * 32 + fg];
            nw2 = W4[(k + 6) * 32 + fg];
            nw3 = W4[(k + 7) * 32 + fg];
        }
#pragma unroll
        for (int r = 0; r < 16; r++) {
            float4 a = As[r0 + r][k >> 2];
            acc[r][0] += a.x * w0.x + a.y * w1.x + a.z * w2.x + a.w * w3.x;
            acc[r][1] += a.x * w0.y + a.y * w1.y + a.z * w2.y + a.w * w3.y;
            acc[r][2] += a.x * w0.z + a.y * w1.z + a.z * w2.z + a.w * w3.z;
            acc[r][3] += a.x * w0.w + a.y * w1.w + a.z * w2.w + a.w * w3.w;
        }
        w0 = nw0; w1 = nw1; w2 = nw2; w3 = nw3;
    }

#pragma unroll
    for (int r = 0; r < 16; r++) {
        int gr = row0 + r0 + r;
        if (gr < nrows) {
            float nov = no[gr];
            half4 o;
            o.x = (_Float16)(acc[r][0] * nov);
            o.y = (_Float16)(acc[r][1] * nov);
            o.z = (_Float16)(acc[r][2] * nov);
            o.w = (_Float16)(acc[r][3] * nov);
            Zh[gr * 32 + fg] = o;
        }
    }
}

// ---------------- aggregation: h'[v] = relu(ni[v]*sum_u zh[u] + b) ----------------
// 4 nodes per 128-thread block; 32 lanes per node; unroll x4 for MLP.
__global__ __launch_bounds__(128) void k_agg(const half4* __restrict__ Zh,
                                             const int* __restrict__ offs,
                                             const int* __restrict__ csr,
                                             const float* __restrict__ ni,
                                             const float4* __restrict__ b4,
                                             float4* __restrict__ H4) {
    int v = blockIdx.x * 4 + (threadIdx.x >> 5);
    int c = threadIdx.x & 31;
    int s = offs[v];
    int e = offs[v + 1];
    float ax = 0.f, ay = 0.f, az = 0.f, aw = 0.f;
    float px = 0.f, py = 0.f, pz = 0.f, pw = 0.f;
    int i = s;
    for (; i + 4 <= e; i += 4) {
        int u0 = csr[i];
        int u1 = csr[i + 1];
        int u2 = csr[i + 2];
        int u3 = csr[i + 3];
        half4 z0 = Zh[u0 * 32 + c];
        half4 z1 = Zh[u1 * 32 + c];
        half4 z2 = Zh[u2 * 32 + c];
        half4 z3 = Zh[u3 * 32 + c];
        ax += (float)z0.x + (float)z1.x;
        ay += (float)z0.y + (float)z1.y;
        az += (float)z0.z + (float)z1.z;
        aw += (float)z0.w + (float)z1.w;
        px += (float)z2.x + (float)z3.x;
        py += (float)z2.y + (float)z3.y;
        pz += (float)z2.z + (float)z3.z;
        pw += (float)z2.w + (float)z3.w;
    }
    for (; i < e; i++) {
        int u = csr[i];
        half4 zr = Zh[u * 32 + c];
        ax += (float)zr.x;
        ay += (float)zr.y;
        az += (float)zr.z;
        aw += (float)zr.w;
    }
    ax += px; ay += py; az += pz; aw += pw;
    float niv = ni[v];
    float4 bb = b4[c];
    float4 r;
    r.x = fmaxf(ax * niv + bb.x, 0.f);
    r.y = fmaxf(ay * niv + bb.y, 0.f);
    r.z = fmaxf(az * niv + bb.z, 0.f);
    r.w = fmaxf(aw * niv + bb.w, 0.f);
    H4[v * 32 + c] = r;
}

// ---------------- per-graph readout (node2graph is sorted) ----------------
__global__ __launch_bounds__(128) void k_readout(const float* __restrict__ H,
                                                 const int* __restrict__ n2g,
                                                 float* __restrict__ g) {
    int f = threadIdx.x;
    int v0 = blockIdx.x * 128;
    int vend = v0 + 128;
    if (vend > NN) vend = NN;
    float acc = 0.f;
    int cur = n2g[v0];
    for (int v = v0; v < vend; v++) {
        int gid = n2g[v];
        if (gid != cur) {
            atomicAdd(&g[cur * 128 + f], acc);
            acc = 0.f;
            cur = gid;
        }
        acc += H[v * 128 + f];
    }
    atomicAdd(&g[cur * 128 + f], acc);
}

// ---------------- MLP head: out = relu(g@Wm1+bm1)@Wm2 + bm2 ----------------
__global__ __launch_bounds__(128) void k_head(const float* __restrict__ g,
                                              const float* __restrict__ Wm1,
                                              const float* __restrict__ bm1,
                                              const float* __restrict__ Wm2,
                                              const float* __restrict__ bm2,
                                              float* __restrict__ out) {
    __shared__ float gs[128];
    __shared__ float red[128];
    int gi = blockIdx.x;
    int f = threadIdx.x;
    gs[f] = g[gi * 128 + f];
    __syncthreads();
    float acc = bm1[f];
    for (int k = 0; k < 128; k++) acc += gs[k] * Wm1[k * 128 + f];
    float h1 = fmaxf(acc, 0.f);
    red[f] = h1 * Wm2[f];
    __syncthreads();
    for (int s2 = 64; s2 > 0; s2 >>= 1) {
        if (f < s2) red[f] += red[f + s2];
        __syncthreads();
    }
    if (f == 0) out[gi] = red[0] + bm2[0];
}

extern "C" void kernel_launch(void* const* d_in, const int* in_sizes, int n_in,
                              void* d_out, int out_size, void* d_ws, size_t ws_size,
                              hipStream_t stream) {
    const float* x   = (const float*)d_in[0];
    const int*   src = (const int*)d_in[1];
    const int*   dst = (const int*)d_in[2];
    const int*   n2g = (const int*)d_in[3];
    const float* W0  = (const float*)d_in[4];
    const float* b0  = (const float*)d_in[5];
    const float* W1  = (const float*)d_in[6];
    const float* b1  = (const float*)d_in[7];
    const float* W2  = (const float*)d_in[8];
    const float* b2  = (const float*)d_in[9];
    const float* Wm1 = (const float*)d_in[10];
    const float* bm1 = (const float*)d_in[11];
    const float* Wm2 = (const float*)d_in[12];
    const float* bm2 = (const float*)d_in[13];
    float* out = (float*)d_out;

    char* p = (char*)d_ws;
    auto carve = [&](size_t bytes) -> char* {
        char* r = p;
        p += (bytes + 255) & ~(size_t)255;
        return r;
    };
    half4* zh     = (half4*)carve((size_t)NN * HD * 2);
    float* h      = (float*)carve((size_t)NN * HD * 4);
    float* no     = (float*)carve((size_t)NN * 4);
    float* ni     = (float*)carve((size_t)NN * 4);
    int*   offs   = (int*)carve((size_t)(NN + 1) * 4);
    int*   csr    = (int*)carve((size_t)NE * 4);
    int*   Hh     = (int*)carve((size_t)LH * 4);
    int*   bsum   = (int*)carve((size_t)512 * 4);
    int2*  dpart  = (int2*)carve((size_t)NE * 8);
    int*   spart  = (int*)carve((size_t)NE * 4);
    float* g      = (float*)carve((size_t)NG * HD * 4);

    hipMemsetAsync(g, 0, (size_t)NG * HD * 4, stream);

    // graph build: bucketed counting sort (LDS atomics, contained writes)
    int scan_blocks = (LH + 255) / 256;  // 480 <= 512
    k_hist<<<NC, 256, 0, stream>>>(src, dst, Hh);
    k_scan1g<<<scan_blocks, 256, 0, stream>>>(Hh, bsum, LH);
    k_scan2<<<1, 512, 0, stream>>>(bsum, scan_blocks);
    k_scan3g<<<scan_blocks, 256, 0, stream>>>(Hh, bsum, LH);
    k_scatter<<<NC, 256, 0, stream>>>(src, dst, Hh, dpart, spart);
    k_bucket<<<2 * NBK, 256, 0, stream>>>(dpart, spart, Hh, offs, csr, ni, no);

    int gemm_blocks = (NN + 127) / 128;

    // layer 0
    k_gemm<<<gemm_blocks, 256, 0, stream>>>(x, W0, no, zh, NN);
    k_agg<<<NN / 4, 128, 0, stream>>>(zh, offs, csr, ni, (const float4*)b0, (float4*)h);
    // layer 1
    k_gemm<<<gemm_blocks, 256, 0, stream>>>(h, W1, no, zh, NN);
    k_agg<<<NN / 4, 128, 0, stream>>>(zh, offs, csr, ni, (const float4*)b1, (float4*)h);
    // layer 2
    k_gemm<<<gemm_blocks, 256, 0, stream>>>(h, W2, no, zh, NN);
    k_agg<<<NN / 4, 128, 0, stream>>>(zh, offs, csr, ni, (const float4*)b2, (float4*)h);

    k_readout<<<(NN + 127) / 128, 128, 0, stream>>>(h, n2g, g);
    k_head<<<NG, 128, 0, stream>>>(g, Wm1, bm1, Wm2, bm2, out);
}

// Round 5
// 463.976 us; speedup vs baseline: 2.0377x; 1.4161x over previous
//
#include <hip/hip_runtime.h>

#define NN 100000
#define NE 1600000
#define NG 512
#define HD 128

#define NBK 196            // node buckets of 512: 196*512 = 100352 >= NN
#define CHUNK 5120         // edges per chunk
#define NC 313             // ceil(NE/CHUNK)
#define LH (2 * NBK * NC)  // 122696 histogram entries (dst part | src part)

typedef _Float16 half4 __attribute__((ext_vector_type(4)));
typedef _Float16 h8 __attribute__((ext_vector_type(8)));
typedef float f32x4 __attribute__((ext_vector_type(4)));

// ---------------- pass A1: per-chunk bucket histograms (dst and src) ----------------
__global__ __launch_bounds__(256) void k_hist(const int* __restrict__ src,
                                              const int* __restrict__ dst,
                                              int* __restrict__ H) {
    __shared__ int hd[NBK], hs[NBK];
    int c = blockIdx.x;
    for (int i = threadIdx.x; i < NBK; i += 256) { hd[i] = 0; hs[i] = 0; }
    __syncthreads();
    int e0 = c * CHUNK;
    int e1 = e0 + CHUNK; if (e1 > NE) e1 = NE;
    for (int e = e0 + threadIdx.x; e < e1; e += 256) {
        atomicAdd(&hd[dst[e] >> 9], 1);
        atomicAdd(&hs[src[e] >> 9], 1);
    }
    __syncthreads();
    for (int i = threadIdx.x; i < NBK; i += 256) {
        H[i * NC + c] = hd[i];
        H[NBK * NC + i * NC + c] = hs[i];
    }
}

// ---------------- generic 3-stage exclusive scan ----------------
__global__ __launch_bounds__(256) void k_scan1g(int* __restrict__ H,
                                                int* __restrict__ bsum, int L) {
    __shared__ int s[256];
    int i = blockIdx.x * 256 + threadIdx.x;
    int v = (i < L) ? H[i] : 0;
    s[threadIdx.x] = v;
    __syncthreads();
    for (int off = 1; off < 256; off <<= 1) {
        int t = (threadIdx.x >= off) ? s[threadIdx.x - off] : 0;
        __syncthreads();
        s[threadIdx.x] += t;
        __syncthreads();
    }
    if (i < L) H[i] = s[threadIdx.x] - v;
    if (threadIdx.x == 255) bsum[blockIdx.x] = s[255];
}

__global__ __launch_bounds__(512) void k_scan2(int* __restrict__ bsum, int nb) {
    __shared__ int s[512];
    int v = (threadIdx.x < nb) ? bsum[threadIdx.x] : 0;
    s[threadIdx.x] = v;
    __syncthreads();
    for (int off = 1; off < 512; off <<= 1) {
        int t = (threadIdx.x >= off) ? s[threadIdx.x - off] : 0;
        __syncthreads();
        s[threadIdx.x] += t;
        __syncthreads();
    }
    if (threadIdx.x < nb) bsum[threadIdx.x] = s[threadIdx.x] - v;
}

__global__ __launch_bounds__(256) void k_scan3g(int* __restrict__ H,
                                                const int* __restrict__ bsum, int L) {
    int i = blockIdx.x * 256 + threadIdx.x;
    if (i < L) H[i] += bsum[i >> 8];
}

// ---------------- pass A2: partition edges into buckets ----------------
__global__ __launch_bounds__(256) void k_scatter(const int* __restrict__ src,
                                                 const int* __restrict__ dst,
                                                 const int* __restrict__ H,
                                                 int2* __restrict__ dpart,
                                                 int* __restrict__ spart) {
    __shared__ int cd[NBK], cs[NBK];
    int c = blockIdx.x;
    for (int i = threadIdx.x; i < NBK; i += 256) {
        cd[i] = H[i * NC + c];
        cs[i] = H[NBK * NC + i * NC + c] - NE;
    }
    __syncthreads();
    int e0 = c * CHUNK;
    int e1 = e0 + CHUNK; if (e1 > NE) e1 = NE;
    for (int e = e0 + threadIdx.x; e < e1; e += 256) {
        int s = src[e], d = dst[e];
        int pd = atomicAdd(&cd[d >> 9], 1);
        dpart[pd] = make_int2(s, d);
        int ps = atomicAdd(&cs[s >> 9], 1);
        spart[ps] = s;
    }
}

// ---------------- pass B: per-bucket degree count, offs, norms, CSR fill ----------------
__global__ __launch_bounds__(256) void k_bucket(const int2* __restrict__ dpart,
                                                const int* __restrict__ spart,
                                                const int* __restrict__ H,
                                                int* __restrict__ offs,
                                                int* __restrict__ csr,
                                                float* __restrict__ ni,
                                                float* __restrict__ no) {
    __shared__ int deg[512];
    __shared__ int cur[512];
    __shared__ int tmp[256];
    int b = blockIdx.x;
    bool isDst = (b < NBK);
    int bb = isDst ? b : b - NBK;
    int start, end;
    if (isDst) {
        start = H[bb * NC];
        end = (bb + 1 < NBK) ? H[(bb + 1) * NC] : NE;
    } else {
        start = H[NBK * NC + bb * NC] - NE;
        end = (bb + 1 < NBK) ? H[NBK * NC + (bb + 1) * NC] - NE : NE;
    }
    for (int i = threadIdx.x; i < 512; i += 256) deg[i] = 0;
    __syncthreads();
    if (isDst) {
        for (int i = start + threadIdx.x; i < end; i += 256)
            atomicAdd(&deg[dpart[i].y & 511], 1);
    } else {
        for (int i = start + threadIdx.x; i < end; i += 256)
            atomicAdd(&deg[spart[i] & 511], 1);
    }
    __syncthreads();
    int vb = bb * 512;
    if (!isDst) {
        for (int i = threadIdx.x; i < 512; i += 256) {
            int v = vb + i;
            if (v < NN) no[v] = rsqrtf(fmaxf((float)deg[i], 1.0f));
        }
        return;
    }
    // exclusive scan of deg[512] with 256 threads
    int t = threadIdx.x;
    int a0 = deg[2 * t], a1 = deg[2 * t + 1];
    int pair = a0 + a1;
    tmp[t] = pair;
    __syncthreads();
    for (int off = 1; off < 256; off <<= 1) {
        int v2 = (t >= off) ? tmp[t - off] : 0;
        __syncthreads();
        tmp[t] += v2;
        __syncthreads();
    }
    int ex = tmp[t] - pair;
    cur[2 * t] = start + ex;
    cur[2 * t + 1] = start + ex + a0;
    __syncthreads();
    for (int i = threadIdx.x; i < 512; i += 256) {
        int v = vb + i;
        if (v < NN) {
            offs[v] = cur[i];
            ni[v] = rsqrtf(fmaxf((float)deg[i], 1.0f));
        }
    }
    if (b == NBK - 1 && threadIdx.x == 0) offs[NN] = NE;
    __syncthreads();
    for (int i = start + threadIdx.x; i < end; i += 256) {
        int2 e = dpart[i];
        int p = atomicAdd(&cur[e.y & 511], 1);
        csr[p] = e.x;
    }
}

// ---------------- W cast+transpose: Bt[w][n][k] = (fp16) W_w[k][n] ----------------
__global__ __launch_bounds__(256) void k_castw(const float* __restrict__ W0,
                                               const float* __restrict__ W1,
                                               const float* __restrict__ W2,
                                               _Float16* __restrict__ Bt) {
    int i = blockIdx.x * 256 + threadIdx.x;  // 3*16384
    if (i >= 3 * 16384) return;
    int w = i >> 14;
    int rem = i & 16383;
    int n = rem >> 7;
    int k = rem & 127;
    const float* W = (w == 0) ? W0 : ((w == 1) ? W1 : W2);
    Bt[i] = (_Float16)W[k * 128 + n];
}

// ---------------- MFMA GEMM: Zh = no[row] * (A @ W), fp16 in, fp32 acc, fp16 out ----
// Block: 256 threads = 4 waves, 64 rows (16/wave). N=K=128 fixed.
// Bt is W transposed (n-major, k-contiguous) fp16; staged in LDS with +8-half row pad
// (raw 256 B stride = 16-way bank conflict; 272 B stride = free 2-way).
template <typename TA>
__global__ __launch_bounds__(256) void k_gemm_mfma(const TA* __restrict__ A,
                                                   const _Float16* __restrict__ Bt,
                                                   const float* __restrict__ no,
                                                   _Float16* __restrict__ Zh,
                                                   int nrows) {
    __shared__ _Float16 Bs[128 * 136];  // 34 KB
    int tid = threadIdx.x;
    {
        const h8* B8 = (const h8*)Bt;
        h8* Bs8 = (h8*)Bs;
        for (int i = tid; i < 2048; i += 256) {
            int n = i >> 4, c = i & 15;
            Bs8[n * 17 + c] = B8[i];
        }
    }

    int wave = tid >> 6;
    int lane = tid & 63;
    int m16 = lane & 15;
    int quad = lane >> 4;
    int rowbase = blockIdx.x * 64 + wave * 16;
    int row = rowbase + m16;
    bool valid = row < nrows;

    // A-fragment: lane holds A[row][kk*32 + quad*8 + j], j=0..7, for kk=0..3
    h8 afrag[4];
    if (valid) {
        if constexpr (sizeof(TA) == 2) {
            const h8* Arow = (const h8*)(A + (size_t)row * 128);
#pragma unroll
            for (int kk = 0; kk < 4; kk++) afrag[kk] = Arow[kk * 4 + quad];
        } else {
            const float4* Arow = (const float4*)(A + (size_t)row * 128);
#pragma unroll
            for (int kk = 0; kk < 4; kk++) {
                float4 lo = Arow[kk * 8 + quad * 2];
                float4 hi = Arow[kk * 8 + quad * 2 + 1];
                h8 a;
                a[0] = (_Float16)lo.x; a[1] = (_Float16)lo.y;
                a[2] = (_Float16)lo.z; a[3] = (_Float16)lo.w;
                a[4] = (_Float16)hi.x; a[5] = (_Float16)hi.y;
                a[6] = (_Float16)hi.z; a[7] = (_Float16)hi.w;
                afrag[kk] = a;
            }
        }
    } else {
#pragma unroll
        for (int kk = 0; kk < 4; kk++) {
            h8 a;
#pragma unroll
            for (int j = 0; j < 8; j++) a[j] = (_Float16)0.f;
            afrag[kk] = a;
        }
    }

    __syncthreads();

    f32x4 acc[8];
#pragma unroll
    for (int nt = 0; nt < 8; nt++) acc[nt] = (f32x4){0.f, 0.f, 0.f, 0.f};

    const h8* Bs8 = (const h8*)Bs;
#pragma unroll
    for (int nt = 0; nt < 8; nt++) {
        const h8* Bp = Bs8 + (size_t)(nt * 16 + m16) * 17;
#pragma unroll
        for (int kk = 0; kk < 4; kk++) {
            acc[nt] = __builtin_amdgcn_mfma_f32_16x16x32_f16(afrag[kk], Bp[kk * 4 + quad],
                                                             acc[nt], 0, 0, 0);
        }
    }

    // C/D layout: col = lane&15, row = quad*4 + reg  [m89-verified]
    float nor[4];
#pragma unroll
    for (int r = 0; r < 4; r++) {
        int grow = rowbase + quad * 4 + r;
        nor[r] = (grow < nrows) ? no[grow] : 0.f;
    }
#pragma unroll
    for (int nt = 0; nt < 8; nt++) {
#pragma unroll
        for (int r = 0; r < 4; r++) {
            int grow = rowbase + quad * 4 + r;
            if (grow < nrows)
                Zh[(size_t)grow * 128 + nt * 16 + m16] = (_Float16)(acc[nt][r] * nor[r]);
        }
    }
}

// ---------------- aggregation: h'[v] = relu(ni[v]*sum_u zh[u] + b), fp16 out ----------------
__global__ __launch_bounds__(128) void k_agg(const half4* __restrict__ Zh,
                                             const int* __restrict__ offs,
                                             const int* __restrict__ csr,
                                             const float* __restrict__ ni,
                                             const float4* __restrict__ b4,
                                             half4* __restrict__ H16) {
    int v = blockIdx.x * 4 + (threadIdx.x >> 5);
    int c = threadIdx.x & 31;
    int s = offs[v];
    int e = offs[v + 1];
    float ax = 0.f, ay = 0.f, az = 0.f, aw = 0.f;
    float px = 0.f, py = 0.f, pz = 0.f, pw = 0.f;
    int i = s;
    for (; i + 4 <= e; i += 4) {
        int u0 = csr[i];
        int u1 = csr[i + 1];
        int u2 = csr[i + 2];
        int u3 = csr[i + 3];
        half4 z0 = Zh[u0 * 32 + c];
        half4 z1 = Zh[u1 * 32 + c];
        half4 z2 = Zh[u2 * 32 + c];
        half4 z3 = Zh[u3 * 32 + c];
        ax += (float)z0.x + (float)z1.x;
        ay += (float)z0.y + (float)z1.y;
        az += (float)z0.z + (float)z1.z;
        aw += (float)z0.w + (float)z1.w;
        px += (float)z2.x + (float)z3.x;
        py += (float)z2.y + (float)z3.y;
        pz += (float)z2.z + (float)z3.z;
        pw += (float)z2.w + (float)z3.w;
    }
    for (; i < e; i++) {
        int u = csr[i];
        half4 zr = Zh[u * 32 + c];
        ax += (float)zr.x;
        ay += (float)zr.y;
        az += (float)zr.z;
        aw += (float)zr.w;
    }
    ax += px; ay += py; az += pz; aw += pw;
    float niv = ni[v];
    float4 bb = b4[c];
    half4 r;
    r.x = (_Float16)fmaxf(ax * niv + bb.x, 0.f);
    r.y = (_Float16)fmaxf(ay * niv + bb.y, 0.f);
    r.z = (_Float16)fmaxf(az * niv + bb.z, 0.f);
    r.w = (_Float16)fmaxf(aw * niv + bb.w, 0.f);
    H16[v * 32 + c] = r;
}

// ---------------- per-graph readout (node2graph is sorted), fp16 in ----------------
__global__ __launch_bounds__(128) void k_readout(const _Float16* __restrict__ H,
                                                 const int* __restrict__ n2g,
                                                 float* __restrict__ g) {
    int f = threadIdx.x;
    int v0 = blockIdx.x * 128;
    int vend = v0 + 128;
    if (vend > NN) vend = NN;
    float acc = 0.f;
    int cur = n2g[v0];
    for (int v = v0; v < vend; v++) {
        int gid = n2g[v];
        if (gid != cur) {
            atomicAdd(&g[cur * 128 + f], acc);
            acc = 0.f;
            cur = gid;
        }
        acc += (float)H[(size_t)v * 128 + f];
    }
    atomicAdd(&g[cur * 128 + f], acc);
}

// ---------------- MLP head: out = relu(g@Wm1+bm1)@Wm2 + bm2 ----------------
__global__ __launch_bounds__(128) void k_head(const float* __restrict__ g,
                                              const float* __restrict__ Wm1,
                                              const float* __restrict__ bm1,
                                              const float* __restrict__ Wm2,
                                              const float* __restrict__ bm2,
                                              float* __restrict__ out) {
    __shared__ float gs[128];
    __shared__ float red[128];
    int gi = blockIdx.x;
    int f = threadIdx.x;
    gs[f] = g[gi * 128 + f];
    __syncthreads();
    float acc = bm1[f];
    for (int k = 0; k < 128; k++) acc += gs[k] * Wm1[k * 128 + f];
    float h1 = fmaxf(acc, 0.f);
    red[f] = h1 * Wm2[f];
    __syncthreads();
    for (int s2 = 64; s2 > 0; s2 >>= 1) {
        if (f < s2) red[f] += red[f + s2];
        __syncthreads();
    }
    if (f == 0) out[gi] = red[0] + bm2[0];
}

extern "C" void kernel_launch(void* const* d_in, const int* in_sizes, int n_in,
                              void* d_out, int out_size, void* d_ws, size_t ws_size,
                              hipStream_t stream) {
    const float* x   = (const float*)d_in[0];
    const int*   src = (const int*)d_in[1];
    const int*   dst = (const int*)d_in[2];
    const int*   n2g = (const int*)d_in[3];
    const float* W0  = (const float*)d_in[4];
    const float* b0  = (const float*)d_in[5];
    const float* W1  = (const float*)d_in[6];
    const float* b1  = (const float*)d_in[7];
    const float* W2  = (const float*)d_in[8];
    const float* b2  = (const float*)d_in[9];
    const float* Wm1 = (const float*)d_in[10];
    const float* bm1 = (const float*)d_in[11];
    const float* Wm2 = (const float*)d_in[12];
    const float* bm2 = (const float*)d_in[13];
    float* out = (float*)d_out;

    char* p = (char*)d_ws;
    auto carve = [&](size_t bytes) -> char* {
        char* r = p;
        p += (bytes + 255) & ~(size_t)255;
        return r;
    };
    _Float16* zh  = (_Float16*)carve((size_t)NN * HD * 2);
    _Float16* h16 = (_Float16*)carve((size_t)NN * HD * 2);
    _Float16* Bt  = (_Float16*)carve((size_t)3 * 128 * 128 * 2);
    float* no     = (float*)carve((size_t)NN * 4);
    float* ni     = (float*)carve((size_t)NN * 4);
    int*   offs   = (int*)carve((size_t)(NN + 1) * 4);
    int*   csr    = (int*)carve((size_t)NE * 4);
    int*   Hh     = (int*)carve((size_t)LH * 4);
    int*   bsum   = (int*)carve((size_t)512 * 4);
    int2*  dpart  = (int2*)carve((size_t)NE * 8);
    int*   spart  = (int*)carve((size_t)NE * 4);
    float* g      = (float*)carve((size_t)NG * HD * 4);

    hipMemsetAsync(g, 0, (size_t)NG * HD * 4, stream);

    // weight cast+transpose (independent of graph build)
    k_castw<<<(3 * 16384 + 255) / 256, 256, 0, stream>>>(W0, W1, W2, Bt);

    // graph build: bucketed counting sort (LDS atomics, contained writes)
    int scan_blocks = (LH + 255) / 256;  // 480 <= 512
    k_hist<<<NC, 256, 0, stream>>>(src, dst, Hh);
    k_scan1g<<<scan_blocks, 256, 0, stream>>>(Hh, bsum, LH);
    k_scan2<<<1, 512, 0, stream>>>(bsum, scan_blocks);
    k_scan3g<<<scan_blocks, 256, 0, stream>>>(Hh, bsum, LH);
    k_scatter<<<NC, 256, 0, stream>>>(src, dst, Hh, dpart, spart);
    k_bucket<<<2 * NBK, 256, 0, stream>>>(dpart, spart, Hh, offs, csr, ni, no);

    int gemm_blocks = (NN + 63) / 64;  // 1563

    // layer 0 (fp32 input, converted in-kernel)
    k_gemm_mfma<float><<<gemm_blocks, 256, 0, stream>>>(x, Bt, no, zh, NN);
    k_agg<<<NN / 4, 128, 0, stream>>>((const half4*)zh, offs, csr, ni,
                                      (const float4*)b0, (half4*)h16);
    // layer 1
    k_gemm_mfma<_Float16><<<gemm_blocks, 256, 0, stream>>>(h16, Bt + 16384, no, zh, NN);
    k_agg<<<NN / 4, 128, 0, stream>>>((const half4*)zh, offs, csr, ni,
                                      (const float4*)b1, (half4*)h16);
    // layer 2
    k_gemm_mfma<_Float16><<<gemm_blocks, 256, 0, stream>>>(h16, Bt + 32768, no, zh, NN);
    k_agg<<<NN / 4, 128, 0, stream>>>((const half4*)zh, offs, csr, ni,
                                      (const float4*)b2, (half4*)h16);

    k_readout<<<(NN + 127) / 128, 128, 0, stream>>>(h16, n2g, g);
    k_head<<<NG, 128, 0, stream>>>(g, Wm1, bm1, Wm2, bm2, out);
}